// Round 13
// baseline (162.400 us; speedup 1.0000x reference)
//
#include <hip/hip_runtime.h>
#include <hip/hip_bf16.h>
#include <stdint.h>

// B=4, C=64, N=16384, K=16, CO=64 (fp32 I/O, int32 idx)
// Cost model (R11/R12): total = ~47us harness fill + sum(kernels) + ~9us/gap.
// 3 dispatches:
//  k1 gemm (MFMA): A=[W1+W2; W2] (128x64 bf16) @ x (64x65536 bf16) -> y1p/y2p pairs
//  k2 gather: pair-packed gather + extremes + striped-atomic stats; LAST block
//             finalizes scale/bias (done-counter) -- no separate reduce dispatch
//  k3 out:    affine + leaky + transpose (B,N,64)->(B,64,N)
#define NDIM 16384
#define KNB 16
#define BNK_F 1048576.0f

typedef __attribute__((ext_vector_type(8))) short bf16x8_t;
typedef __attribute__((ext_vector_type(4))) float f32x4_t;

__device__ inline unsigned pack_bf16(float a, float b) {
    return (unsigned)__bfloat16_as_ushort(__float2bfloat16(a))
         | ((unsigned)__bfloat16_as_ushort(__float2bfloat16(b)) << 16);
}

// ---------------- Kernel 1: MFMA GEMM ----------------
// 1024 blocks x 256 (4 waves). Block: 64-n tile of one batch; waves split n by 16.
// A rows 0..63 = (w1+w2) -> y1 ; rows 64..127 = w2 -> y2.
__global__ __launch_bounds__(256) void gemm_mfma_kernel(
    const float* __restrict__ x,            // (B, 64, N)
    const float* __restrict__ W,            // (64, 128)
    unsigned* __restrict__ y1p,             // (B,N,32) bf16-pairs
    unsigned* __restrict__ y2p,             // (B,N,32) bf16-pairs
    float* __restrict__ statsN,             // (32,128) striped stats - zeroed here
    unsigned* __restrict__ counter)         // done-counter - zeroed here
{
    __shared__ alignas(16) short lds_a[128 * 72];  // row pad 72 -> 2-way-free b128
    __shared__ alignas(16) short lds_b[64 * 72];   // x tile, n-major

    const int tid = threadIdx.x;
    if (blockIdx.x == 0) {
        for (int i = tid; i < 4096; i += 256) statsN[i] = 0.0f;
        if (tid == 0) *counter = 0u;
    }
    const int b  = blockIdx.x >> 8;
    const int n0 = (blockIdx.x & 255) << 6;

    // stage A (bf16): ch<64: w1+w2 ; ch>=64: w2
    for (int i = tid; i < 8192; i += 256) {
        int ch = i >> 6, c = i & 63;
        float a = (ch < 64) ? (W[ch * 128 + c] + W[ch * 128 + 64 + c])
                            : W[(ch - 64) * 128 + 64 + c];
        lds_a[ch * 72 + c] = (short)__bfloat16_as_ushort(__float2bfloat16(a));
    }
    // stage B: x (c-major fp32) -> lds_b[n][c] bf16, packed-pair writes
    {
        const float* xb = x + (size_t)b * 64 * NDIM + n0;
        const int n = tid & 63;
        unsigned* lb32 = (unsigned*)lds_b;
        for (int cp = tid >> 6; cp < 32; cp += 4) {
            int c = cp * 2;
            float x0 = xb[(size_t)c * NDIM + n];
            float x1 = xb[(size_t)(c + 1) * NDIM + n];
            lb32[n * 36 + cp] = pack_bf16(x0, x1);
        }
    }
    __syncthreads();

    const int lane = tid & 63;
    const int w    = tid >> 6;
    const int m    = lane & 15;              // A-row (ch) AND B-col (n) lane index
    const int q    = lane >> 4;              // k-octet / D-row quad
    const int n    = w * 16 + m;

    const bf16x8_t b0 = *(const bf16x8_t*)&lds_b[n * 72 + q * 8];        // k 0..31
    const bf16x8_t b1 = *(const bf16x8_t*)&lds_b[n * 72 + q * 8 + 32];   // k 32..63

    const size_t rowbase = ((size_t)(b * NDIM + n0 + n)) * 32;
    #pragma unroll
    for (int t = 0; t < 8; ++t) {
        const short* ap = &lds_a[(t * 16 + m) * 72 + q * 8];
        bf16x8_t a0 = *(const bf16x8_t*)ap;
        bf16x8_t a1 = *(const bf16x8_t*)(ap + 32);
        f32x4_t acc = {0.f, 0.f, 0.f, 0.f};
        acc = __builtin_amdgcn_mfma_f32_16x16x32_bf16(a0, b0, acc, 0, 0, 0);
        acc = __builtin_amdgcn_mfma_f32_16x16x32_bf16(a1, b1, acc, 0, 0, 0);
        // D: row(ch-in-tile)=q*4+r, col(n)=lane&15 -> 4 consecutive ch = 2 pairs
        unsigned* dst = (t < 4) ? y1p : y2p;
        uint2 pk = { pack_bf16(acc[0], acc[1]), pack_bf16(acc[2], acc[3]) };
        *(uint2*)&dst[rowbase + (t & 3) * 8 + q * 2] = pk;
    }
}

// ---------------- Kernel 2: gather + extremes + stats + inline finalize ----------------
// 2048 blocks x 256, XCD-pinned batches. Striped stats atomics (32 copies).
// Last block (done-counter) sums copies and writes sb[0..63]=scale, [64..127]=bias.
__global__ __launch_bounds__(256, 4) void gather_kernel(
    const unsigned* __restrict__ y1p,        // (B,N,32) bf16-pairs
    const unsigned* __restrict__ y2p,
    const int* __restrict__ ei,              // (B, N, 16)
    const float* __restrict__ gamma,
    const float* __restrict__ beta,
    unsigned* __restrict__ hselp,            // (B,N,32) bf16-pairs
    float* __restrict__ statsN,              // (32,128)
    float* __restrict__ sb,                  // (128)
    unsigned* __restrict__ counter)
{
    const int tid  = threadIdx.x;
    const int w    = __builtin_amdgcn_readfirstlane(tid >> 6);
    const int lane = tid & 63;
    const int half = lane >> 5;
    const int c2   = lane & 31;
    const int g    = blockIdx.x;
    const int xcd  = g & 7;
    const int b    = xcd >> 1;
    const int row0 = b * NDIM + (xcd & 1) * 8192 + (g >> 3) * 32 + w * 8;

    const unsigned sgn0 = (gamma[2 * c2]     >= 0.0f) ? 0x80000000u : 0u;
    const unsigned sgn1 = (gamma[2 * c2 + 1] >= 0.0f) ? 0x80000000u : 0u;
    const unsigned* y2b = y2p + ((size_t)b * NDIM) * 32 + c2;

    float ssum0 = 0.f, ssum1 = 0.f, ssq0 = 0.f, ssq1 = 0.f;
    for (int rp = 0; rp < 8; rp += 2) {
        const int ra = row0 + rp;
        const int* iA = ei + (size_t)ra * KNB;        // wave-uniform -> s_load
        const int* iB = ei + (size_t)(ra + 1) * KNB;
        unsigned u[KNB];
        #pragma unroll
        for (int k = 0; k < KNB; ++k) {
            int j = half ? iB[k] : iA[k];
            u[k] = y2b[(size_t)j * 32];
        }
        const unsigned y1u = y1p[(size_t)(ra + half) * 32 + c2];
        float s20 = 0.f, s21 = 0.f, q20 = 0.f, q21 = 0.f;
        float M0 = -3.402823e38f, M1 = -3.402823e38f;
        #pragma unroll
        for (int k = 0; k < KNB; ++k) {
            unsigned lo = u[k] << 16, hi = u[k] & 0xffff0000u;
            float v0 = __uint_as_float(lo), v1 = __uint_as_float(hi);
            s20 += v0;               s21 += v1;
            q20 = fmaf(v0, v0, q20); q21 = fmaf(v1, v1, q21);
            M0 = fmaxf(M0, __uint_as_float(lo ^ sgn0));
            M1 = fmaxf(M1, __uint_as_float(hi ^ sgn1));
        }
        const float y1lo = __uint_as_float(y1u << 16);
        const float y1hi = __uint_as_float(y1u & 0xffff0000u);
        const float h0 = y1lo - __uint_as_float(__float_as_uint(M0) ^ sgn0);
        const float h1 = y1hi - __uint_as_float(__float_as_uint(M1) ^ sgn1);
        hselp[(size_t)(ra + half) * 32 + c2] = pack_bf16(h0, h1);
        ssum0 += 16.f * y1lo - s20;
        ssum1 += 16.f * y1hi - s21;
        ssq0  += fmaf(fmaf(-2.f, s20, 16.f * y1lo), y1lo, q20);
        ssq1  += fmaf(fmaf(-2.f, s21, 16.f * y1hi), y1hi, q21);
    }

    __shared__ float rs[8][64];
    __shared__ float rq[8][64];
    __shared__ float colsum[128];
    __shared__ int   isLast;
    rs[w * 2 + half][c2 * 2]     = ssum0;
    rs[w * 2 + half][c2 * 2 + 1] = ssum1;
    rq[w * 2 + half][c2 * 2]     = ssq0;
    rq[w * 2 + half][c2 * 2 + 1] = ssq1;
    __syncthreads();
    if (tid < 128) {
        const int c = tid & 63;
        float v = 0.f;
        if (tid < 64) { for (int r = 0; r < 8; ++r) v += rs[r][c]; }
        else          { for (int r = 0; r < 8; ++r) v += rq[r][c]; }
        atomicAdd(&statsN[(g & 31) * 128 + tid], v);   // 32-way striped: low contention
    }
    __syncthreads();                          // drains the atomics (barrier waitcnt)
    if (tid == 0) {
        __threadfence();
        isLast = (atomicAdd(counter, 1u) == 2047u);
    }
    __syncthreads();
    if (isLast) {
        __threadfence();
        if (tid < 128) {
            float v = 0.f;
            #pragma unroll
            for (int i = 0; i < 32; ++i)
                v += __hip_atomic_load(&statsN[i * 128 + tid],
                                       __ATOMIC_RELAXED, __HIP_MEMORY_SCOPE_AGENT);
            colsum[tid] = v;
        }
        __syncthreads();
        if (tid < 64) {
            float mean = colsum[tid] * (1.0f / BNK_F);
            float var  = colsum[64 + tid] * (1.0f / BNK_F) - mean * mean;
            float s    = gamma[tid] * rsqrtf(var + 1e-5f);
            sb[tid]      = s;
            sb[64 + tid] = beta[tid] - mean * s;
        }
    }
}

// ---------------- Kernel 3: affine + leaky + transpose ----------------
__global__ __launch_bounds__(256) void out_kernel(
    const unsigned* __restrict__ hselp,      // (B,N,32) bf16-pairs
    const float* __restrict__ sb,
    float* __restrict__ out)                 // (B, 64, N)
{
    __shared__ float tile[64 * 65];
    __shared__ float sc[64], bi[64];
    const int tid = threadIdx.x;
    if (tid < 128) {
        if (tid < 64) sc[tid] = sb[tid];
        else          bi[tid - 64] = sb[tid];
    }
    __syncthreads();

    const int b  = blockIdx.x >> 8;
    const int n0 = (blockIdx.x & 255) << 6;
    const size_t bn0 = (size_t)b * NDIM + n0;
    const int c2 = tid & 31;

    for (int r = tid >> 5; r < 64; r += 8) {
        unsigned u = hselp[(bn0 + r) * 32 + c2];
        float v0 = fmaf(sc[2 * c2],     __uint_as_float(u << 16),          bi[2 * c2]);
        float v1 = fmaf(sc[2 * c2 + 1], __uint_as_float(u & 0xffff0000u), bi[2 * c2 + 1]);
        v0 = (v0 >= 0.f) ? v0 : 0.2f * v0;
        v1 = (v1 >= 0.f) ? v1 : 0.2f * v1;
        tile[r * 65 + 2 * c2]     = v0;
        tile[r * 65 + 2 * c2 + 1] = v1;
    }
    __syncthreads();
    const int lane = tid & 63;
    for (int o = tid >> 6; o < 64; o += 4)
        out[((size_t)(b * 64 + o) << 14) + n0 + lane] = tile[lane * 65 + o];
}

extern "C" void kernel_launch(void* const* d_in, const int* in_sizes, int n_in,
                              void* d_out, int out_size, void* d_ws, size_t ws_size,
                              hipStream_t stream) {
    const float* x     = (const float*)d_in[0];
    const int*   ei    = (const int*)d_in[1];
    const float* W     = (const float*)d_in[2];
    const float* gamma = (const float*)d_in[3];
    const float* beta  = (const float*)d_in[4];
    float* out = (float*)d_out;

    char* ws = (char*)d_ws;
    unsigned* y1p     = (unsigned*)(ws);                       // 8 MiB (bf16 pairs)
    unsigned* y2p     = (unsigned*)(ws + 8388608);             // 8 MiB
    unsigned* hselp   = (unsigned*)(ws + 16777216);            // 8 MiB
    float*    statsN  = (float*)(ws + 25165824);               // 16 KiB (32x128)
    float*    sb      = (float*)(ws + 25165824 + 16384);       // 512 B
    unsigned* counter = (unsigned*)(ws + 25165824 + 16384 + 512);

    gemm_mfma_kernel <<<dim3(1024), dim3(256), 0, stream>>>(x, W, y1p, y2p, statsN, counter);
    gather_kernel    <<<dim3(2048), dim3(256), 0, stream>>>(y1p, y2p, ei, gamma, beta,
                                                            hselp, statsN, sb, counter);
    out_kernel       <<<dim3(1024), dim3(256), 0, stream>>>(hselp, sb, out);
}

// Round 14
// 111.295 us; speedup vs baseline: 1.4592x; 1.4592x over previous
//
#include <hip/hip_runtime.h>
#include <hip/hip_bf16.h>
#include <stdint.h>

// B=4, C=64, N=16384, K=16, CO=64 (fp32 I/O, int32 idx)
// 3 dispatches, NO device fences (R13 lesson: __threadfence = L2 writeback x2048 blocks
// = +35us). Striped stats atomics (R13-proven cheap); out-kernel folds the reduce.
//  k1 gemm (MFMA): A=[W1+W2; W2] (128x64 bf16) @ x-tile -> y1p/y2p bf16-pairs
//  k2 gather: pair-packed gather + extremes + striped statsN atomicAdd
//  k3 out: prologue reduces statsN(32x128)->scale/bias, then affine+leaky+transpose
#define NDIM 16384
#define KNB 16
#define BNK_F 1048576.0f

typedef __attribute__((ext_vector_type(8))) short bf16x8_t;
typedef __attribute__((ext_vector_type(4))) float f32x4_t;

__device__ inline unsigned pack_bf16(float a, float b) {
    return (unsigned)__bfloat16_as_ushort(__float2bfloat16(a))
         | ((unsigned)__bfloat16_as_ushort(__float2bfloat16(b)) << 16);
}

// ---------------- Kernel 1: MFMA GEMM (R13-proven) ----------------
// 1024 blocks x 256 (4 waves). Block: 64-n tile of one batch; waves split n by 16.
// A rows 0..63 = (w1+w2) -> y1 ; rows 64..127 = w2 -> y2.
__global__ __launch_bounds__(256) void gemm_mfma_kernel(
    const float* __restrict__ x,            // (B, 64, N)
    const float* __restrict__ W,            // (64, 128)
    unsigned* __restrict__ y1p,             // (B,N,32) bf16-pairs
    unsigned* __restrict__ y2p,             // (B,N,32) bf16-pairs
    float* __restrict__ statsN)             // (32,128) striped stats - zeroed here
{
    __shared__ alignas(16) short lds_a[128 * 72];  // row pad 72 -> 2-way-free b128
    __shared__ alignas(16) short lds_b[64 * 72];   // x tile, n-major

    const int tid = threadIdx.x;
    if (blockIdx.x == 0) {
        for (int i = tid; i < 4096; i += 256) statsN[i] = 0.0f;
    }
    const int b  = blockIdx.x >> 8;
    const int n0 = (blockIdx.x & 255) << 6;

    // stage A (bf16): ch<64: w1+w2 ; ch>=64: w2
    for (int i = tid; i < 8192; i += 256) {
        int ch = i >> 6, c = i & 63;
        float a = (ch < 64) ? (W[ch * 128 + c] + W[ch * 128 + 64 + c])
                            : W[(ch - 64) * 128 + 64 + c];
        lds_a[ch * 72 + c] = (short)__bfloat16_as_ushort(__float2bfloat16(a));
    }
    // stage B: x (c-major fp32) -> lds_b[n][c] bf16, packed-pair writes
    {
        const float* xb = x + (size_t)b * 64 * NDIM + n0;
        const int n = tid & 63;
        unsigned* lb32 = (unsigned*)lds_b;
        for (int cp = tid >> 6; cp < 32; cp += 4) {
            int c = cp * 2;
            float x0 = xb[(size_t)c * NDIM + n];
            float x1 = xb[(size_t)(c + 1) * NDIM + n];
            lb32[n * 36 + cp] = pack_bf16(x0, x1);
        }
    }
    __syncthreads();

    const int lane = tid & 63;
    const int w    = tid >> 6;
    const int m    = lane & 15;              // A-row (ch) AND B-col (n) lane index
    const int q    = lane >> 4;              // k-octet / D-row quad
    const int n    = w * 16 + m;

    const bf16x8_t b0 = *(const bf16x8_t*)&lds_b[n * 72 + q * 8];        // k 0..31
    const bf16x8_t b1 = *(const bf16x8_t*)&lds_b[n * 72 + q * 8 + 32];   // k 32..63

    const size_t rowbase = ((size_t)(b * NDIM + n0 + n)) * 32;
    #pragma unroll
    for (int t = 0; t < 8; ++t) {
        const short* ap = &lds_a[(t * 16 + m) * 72 + q * 8];
        bf16x8_t a0 = *(const bf16x8_t*)ap;
        bf16x8_t a1 = *(const bf16x8_t*)(ap + 32);
        f32x4_t acc = {0.f, 0.f, 0.f, 0.f};
        acc = __builtin_amdgcn_mfma_f32_16x16x32_bf16(a0, b0, acc, 0, 0, 0);
        acc = __builtin_amdgcn_mfma_f32_16x16x32_bf16(a1, b1, acc, 0, 0, 0);
        // D: row(ch-in-tile)=q*4+r, col(n)=lane&15 -> 4 consecutive ch = 2 pairs
        unsigned* dst = (t < 4) ? y1p : y2p;
        uint2 pk = { pack_bf16(acc[0], acc[1]), pack_bf16(acc[2], acc[3]) };
        *(uint2*)&dst[rowbase + (t & 3) * 8 + q * 2] = pk;
    }
}

// ---------------- Kernel 2: gather + extremes + striped stats ----------------
// 2048 blocks x 256, XCD-pinned batches. 32-way striped atomics, no fence.
__global__ __launch_bounds__(256, 4) void gather_kernel(
    const unsigned* __restrict__ y1p,        // (B,N,32) bf16-pairs
    const unsigned* __restrict__ y2p,
    const int* __restrict__ ei,              // (B, N, 16)
    const float* __restrict__ gamma,
    unsigned* __restrict__ hselp,            // (B,N,32) bf16-pairs
    float* __restrict__ statsN)              // (32,128)
{
    const int tid  = threadIdx.x;
    const int w    = __builtin_amdgcn_readfirstlane(tid >> 6);
    const int lane = tid & 63;
    const int half = lane >> 5;
    const int c2   = lane & 31;
    const int g    = blockIdx.x;
    const int xcd  = g & 7;
    const int b    = xcd >> 1;
    const int row0 = b * NDIM + (xcd & 1) * 8192 + (g >> 3) * 32 + w * 8;

    const unsigned sgn0 = (gamma[2 * c2]     >= 0.0f) ? 0x80000000u : 0u;
    const unsigned sgn1 = (gamma[2 * c2 + 1] >= 0.0f) ? 0x80000000u : 0u;
    const unsigned* y2b = y2p + ((size_t)b * NDIM) * 32 + c2;

    float ssum0 = 0.f, ssum1 = 0.f, ssq0 = 0.f, ssq1 = 0.f;
    for (int rp = 0; rp < 8; rp += 2) {
        const int ra = row0 + rp;
        const int* iA = ei + (size_t)ra * KNB;        // wave-uniform -> s_load
        const int* iB = ei + (size_t)(ra + 1) * KNB;
        unsigned u[KNB];
        #pragma unroll
        for (int k = 0; k < KNB; ++k) {
            int j = half ? iB[k] : iA[k];
            u[k] = y2b[(size_t)j * 32];
        }
        const unsigned y1u = y1p[(size_t)(ra + half) * 32 + c2];
        float s20 = 0.f, s21 = 0.f, q20 = 0.f, q21 = 0.f;
        float M0 = -3.402823e38f, M1 = -3.402823e38f;
        #pragma unroll
        for (int k = 0; k < KNB; ++k) {
            unsigned lo = u[k] << 16, hi = u[k] & 0xffff0000u;
            float v0 = __uint_as_float(lo), v1 = __uint_as_float(hi);
            s20 += v0;               s21 += v1;
            q20 = fmaf(v0, v0, q20); q21 = fmaf(v1, v1, q21);
            M0 = fmaxf(M0, __uint_as_float(lo ^ sgn0));
            M1 = fmaxf(M1, __uint_as_float(hi ^ sgn1));
        }
        const float y1lo = __uint_as_float(y1u << 16);
        const float y1hi = __uint_as_float(y1u & 0xffff0000u);
        const float h0 = y1lo - __uint_as_float(__float_as_uint(M0) ^ sgn0);
        const float h1 = y1hi - __uint_as_float(__float_as_uint(M1) ^ sgn1);
        hselp[(size_t)(ra + half) * 32 + c2] = pack_bf16(h0, h1);
        ssum0 += 16.f * y1lo - s20;
        ssum1 += 16.f * y1hi - s21;
        ssq0  += fmaf(fmaf(-2.f, s20, 16.f * y1lo), y1lo, q20);
        ssq1  += fmaf(fmaf(-2.f, s21, 16.f * y1hi), y1hi, q21);
    }

    __shared__ float rs[8][64];
    __shared__ float rq[8][64];
    rs[w * 2 + half][c2 * 2]     = ssum0;
    rs[w * 2 + half][c2 * 2 + 1] = ssum1;
    rq[w * 2 + half][c2 * 2]     = ssq0;
    rq[w * 2 + half][c2 * 2 + 1] = ssq1;
    __syncthreads();
    if (tid < 128) {
        const int c = tid & 63;
        float v = 0.f;
        if (tid < 64) { for (int r = 0; r < 8; ++r) v += rs[r][c]; }
        else          { for (int r = 0; r < 8; ++r) v += rq[r][c]; }
        atomicAdd(&statsN[(g & 31) * 128 + tid], v);   // striped: ~64 adds/line
    }
}

// ---------------- Kernel 3: reduce-in-prologue + affine + leaky + transpose ----------------
__global__ __launch_bounds__(256) void out_kernel(
    const unsigned* __restrict__ hselp,      // (B,N,32) bf16-pairs
    const float* __restrict__ statsN,        // (32,128)
    const float* __restrict__ gamma,
    const float* __restrict__ beta,
    float* __restrict__ out)                 // (B, 64, N)
{
    __shared__ float tile[64 * 65];
    __shared__ float colsum[128];
    __shared__ float sc[64], bi[64];
    const int tid = threadIdx.x;

    if (tid < 128) {
        float v = 0.f;
        #pragma unroll
        for (int i = 0; i < 32; ++i) v += statsN[i * 128 + tid];
        colsum[tid] = v;
    }
    __syncthreads();
    if (tid < 64) {
        float mean = colsum[tid] * (1.0f / BNK_F);
        float var  = colsum[64 + tid] * (1.0f / BNK_F) - mean * mean;
        float s    = gamma[tid] * rsqrtf(var + 1e-5f);
        sc[tid] = s;
        bi[tid] = beta[tid] - mean * s;
    }
    __syncthreads();

    const int b  = blockIdx.x >> 8;
    const int n0 = (blockIdx.x & 255) << 6;
    const size_t bn0 = (size_t)b * NDIM + n0;
    const int c2 = tid & 31;

    for (int r = tid >> 5; r < 64; r += 8) {
        unsigned u = hselp[(bn0 + r) * 32 + c2];
        float v0 = fmaf(sc[2 * c2],     __uint_as_float(u << 16),          bi[2 * c2]);
        float v1 = fmaf(sc[2 * c2 + 1], __uint_as_float(u & 0xffff0000u), bi[2 * c2 + 1]);
        v0 = (v0 >= 0.f) ? v0 : 0.2f * v0;
        v1 = (v1 >= 0.f) ? v1 : 0.2f * v1;
        tile[r * 65 + 2 * c2]     = v0;
        tile[r * 65 + 2 * c2 + 1] = v1;
    }
    __syncthreads();
    const int lane = tid & 63;
    for (int o = tid >> 6; o < 64; o += 4)
        out[((size_t)(b * 64 + o) << 14) + n0 + lane] = tile[lane * 65 + o];
}

extern "C" void kernel_launch(void* const* d_in, const int* in_sizes, int n_in,
                              void* d_out, int out_size, void* d_ws, size_t ws_size,
                              hipStream_t stream) {
    const float* x     = (const float*)d_in[0];
    const int*   ei    = (const int*)d_in[1];
    const float* W     = (const float*)d_in[2];
    const float* gamma = (const float*)d_in[3];
    const float* beta  = (const float*)d_in[4];
    float* out = (float*)d_out;

    char* ws = (char*)d_ws;
    unsigned* y1p    = (unsigned*)(ws);                       // 8 MiB (bf16 pairs)
    unsigned* y2p    = (unsigned*)(ws + 8388608);             // 8 MiB
    unsigned* hselp  = (unsigned*)(ws + 16777216);            // 8 MiB
    float*    statsN = (float*)(ws + 25165824);               // 16 KiB (32x128)

    gemm_mfma_kernel <<<dim3(1024), dim3(256), 0, stream>>>(x, W, y1p, y2p, statsN);
    gather_kernel    <<<dim3(2048), dim3(256), 0, stream>>>(y1p, y2p, ei, gamma, hselp, statsN);
    out_kernel       <<<dim3(1024), dim3(256), 0, stream>>>(hselp, statsN, gamma, beta, out);
}

// Round 15
// 110.737 us; speedup vs baseline: 1.4665x; 1.0050x over previous
//
#include <hip/hip_runtime.h>
#include <hip/hip_bf16.h>
#include <stdint.h>

// B=4, C=64, N=16384, K=16, CO=64 (fp32 I/O, int32 idx)
// 3 dispatches (R14 structure), gather upgraded to 2 interleaved row-pairs
// (32 outstanding gathers/wave) under launch_bounds(256,4) - no spill (R9 rule).
//  k1 gemm (MFMA): A=[W1+W2; W2] (128x64 bf16) @ x-tile -> y1p/y2p bf16-pairs
//  k2 gather: pair-packed gather + extremes + striped statsN atomicAdd
//  k3 out: prologue reduces statsN(32x128)->scale/bias, then affine+leaky+transpose
#define NDIM 16384
#define KNB 16
#define BNK_F 1048576.0f

typedef __attribute__((ext_vector_type(8))) short bf16x8_t;
typedef __attribute__((ext_vector_type(4))) float f32x4_t;

__device__ inline unsigned pack_bf16(float a, float b) {
    return (unsigned)__bfloat16_as_ushort(__float2bfloat16(a))
         | ((unsigned)__bfloat16_as_ushort(__float2bfloat16(b)) << 16);
}

// ---------------- Kernel 1: MFMA GEMM (R13/R14-proven) ----------------
__global__ __launch_bounds__(256) void gemm_mfma_kernel(
    const float* __restrict__ x,            // (B, 64, N)
    const float* __restrict__ W,            // (64, 128)
    unsigned* __restrict__ y1p,             // (B,N,32) bf16-pairs
    unsigned* __restrict__ y2p,             // (B,N,32) bf16-pairs
    float* __restrict__ statsN)             // (32,128) striped stats - zeroed here
{
    __shared__ alignas(16) short lds_a[128 * 72];  // row pad 72 -> 2-way-free b128
    __shared__ alignas(16) short lds_b[64 * 72];   // x tile, n-major

    const int tid = threadIdx.x;
    if (blockIdx.x == 0) {
        for (int i = tid; i < 4096; i += 256) statsN[i] = 0.0f;
    }
    const int b  = blockIdx.x >> 8;
    const int n0 = (blockIdx.x & 255) << 6;

    // stage A (bf16): ch<64: w1+w2 ; ch>=64: w2
    for (int i = tid; i < 8192; i += 256) {
        int ch = i >> 6, c = i & 63;
        float a = (ch < 64) ? (W[ch * 128 + c] + W[ch * 128 + 64 + c])
                            : W[(ch - 64) * 128 + 64 + c];
        lds_a[ch * 72 + c] = (short)__bfloat16_as_ushort(__float2bfloat16(a));
    }
    // stage B: x (c-major fp32) -> lds_b[n][c] bf16, packed-pair writes
    {
        const float* xb = x + (size_t)b * 64 * NDIM + n0;
        const int n = tid & 63;
        unsigned* lb32 = (unsigned*)lds_b;
        for (int cp = tid >> 6; cp < 32; cp += 4) {
            int c = cp * 2;
            float x0 = xb[(size_t)c * NDIM + n];
            float x1 = xb[(size_t)(c + 1) * NDIM + n];
            lb32[n * 36 + cp] = pack_bf16(x0, x1);
        }
    }
    __syncthreads();

    const int lane = tid & 63;
    const int w    = tid >> 6;
    const int m    = lane & 15;              // A-row (ch) AND B-col (n) lane index
    const int q    = lane >> 4;              // k-octet / D-row quad
    const int n    = w * 16 + m;

    const bf16x8_t b0 = *(const bf16x8_t*)&lds_b[n * 72 + q * 8];        // k 0..31
    const bf16x8_t b1 = *(const bf16x8_t*)&lds_b[n * 72 + q * 8 + 32];   // k 32..63

    const size_t rowbase = ((size_t)(b * NDIM + n0 + n)) * 32;
    #pragma unroll
    for (int t = 0; t < 8; ++t) {
        const short* ap = &lds_a[(t * 16 + m) * 72 + q * 8];
        bf16x8_t a0 = *(const bf16x8_t*)ap;
        bf16x8_t a1 = *(const bf16x8_t*)(ap + 32);
        f32x4_t acc = {0.f, 0.f, 0.f, 0.f};
        acc = __builtin_amdgcn_mfma_f32_16x16x32_bf16(a0, b0, acc, 0, 0, 0);
        acc = __builtin_amdgcn_mfma_f32_16x16x32_bf16(a1, b1, acc, 0, 0, 0);
        // D: row(ch-in-tile)=q*4+r, col(n)=lane&15 -> 4 consecutive ch = 2 pairs
        unsigned* dst = (t < 4) ? y1p : y2p;
        uint2 pk = { pack_bf16(acc[0], acc[1]), pack_bf16(acc[2], acc[3]) };
        *(uint2*)&dst[rowbase + (t & 3) * 8 + q * 2] = pk;
    }
}

// ---------------- Kernel 2: gather, 2 interleaved row-pairs ----------------
// 2048 blocks x 256, XCD-pinned batches. 32 outstanding gathers/wave.
__global__ __launch_bounds__(256, 4) void gather_kernel(
    const unsigned* __restrict__ y1p,        // (B,N,32) bf16-pairs
    const unsigned* __restrict__ y2p,
    const int* __restrict__ ei,              // (B, N, 16)
    const float* __restrict__ gamma,
    unsigned* __restrict__ hselp,            // (B,N,32) bf16-pairs
    float* __restrict__ statsN)              // (32,128)
{
    const int tid  = threadIdx.x;
    const int w    = __builtin_amdgcn_readfirstlane(tid >> 6);
    const int lane = tid & 63;
    const int half = lane >> 5;
    const int c2   = lane & 31;
    const int g    = blockIdx.x;
    const int xcd  = g & 7;
    const int b    = xcd >> 1;
    const int row0 = b * NDIM + (xcd & 1) * 8192 + (g >> 3) * 32 + w * 8;

    const unsigned sgn0 = (gamma[2 * c2]     >= 0.0f) ? 0x80000000u : 0u;
    const unsigned sgn1 = (gamma[2 * c2 + 1] >= 0.0f) ? 0x80000000u : 0u;
    const unsigned* y2b = y2p + ((size_t)b * NDIM) * 32 + c2;

    float ssum0 = 0.f, ssum1 = 0.f, ssq0 = 0.f, ssq1 = 0.f;

    for (int rp = 0; rp < 8; rp += 4) {
        const int ra = row0 + rp;            // pair0: rows ra, ra+1
        const int rb = ra + 2;               // pair1: rows rb, rb+1
        const int* iA = ei + (size_t)ra * KNB;        // wave-uniform -> s_load
        const int* iB = ei + (size_t)(ra + 1) * KNB;
        const int* iC = ei + (size_t)rb * KNB;
        const int* iD = ei + (size_t)(rb + 1) * KNB;

        unsigned u0[KNB], u1[KNB];
        #pragma unroll
        for (int k = 0; k < KNB; ++k) {
            int j = half ? iB[k] : iA[k];
            u0[k] = y2b[(size_t)j * 32];
        }
        #pragma unroll
        for (int k = 0; k < KNB; ++k) {
            int j = half ? iD[k] : iC[k];
            u1[k] = y2b[(size_t)j * 32];
        }
        const unsigned y1u0 = y1p[(size_t)(ra + half) * 32 + c2];
        const unsigned y1u1 = y1p[(size_t)(rb + half) * 32 + c2];

        #pragma unroll 2
        for (int p = 0; p < 2; ++p) {
            const unsigned* u = (p == 0) ? u0 : u1;
            const unsigned y1u = (p == 0) ? y1u0 : y1u1;
            const int rw = ((p == 0) ? ra : rb) + half;

            float s20 = 0.f, s21 = 0.f, q20 = 0.f, q21 = 0.f;
            float M0 = -3.402823e38f, M1 = -3.402823e38f;
            #pragma unroll
            for (int k = 0; k < KNB; ++k) {
                unsigned lo = u[k] << 16, hi = u[k] & 0xffff0000u;
                float v0 = __uint_as_float(lo), v1 = __uint_as_float(hi);
                s20 += v0;               s21 += v1;
                q20 = fmaf(v0, v0, q20); q21 = fmaf(v1, v1, q21);
                M0 = fmaxf(M0, __uint_as_float(lo ^ sgn0));
                M1 = fmaxf(M1, __uint_as_float(hi ^ sgn1));
            }
            const float y1lo = __uint_as_float(y1u << 16);
            const float y1hi = __uint_as_float(y1u & 0xffff0000u);
            const float h0 = y1lo - __uint_as_float(__float_as_uint(M0) ^ sgn0);
            const float h1 = y1hi - __uint_as_float(__float_as_uint(M1) ^ sgn1);
            hselp[(size_t)rw * 32 + c2] = pack_bf16(h0, h1);
            ssum0 += 16.f * y1lo - s20;
            ssum1 += 16.f * y1hi - s21;
            ssq0  += fmaf(fmaf(-2.f, s20, 16.f * y1lo), y1lo, q20);
            ssq1  += fmaf(fmaf(-2.f, s21, 16.f * y1hi), y1hi, q21);
        }
    }

    __shared__ float rs[8][64];
    __shared__ float rq[8][64];
    rs[w * 2 + half][c2 * 2]     = ssum0;
    rs[w * 2 + half][c2 * 2 + 1] = ssum1;
    rq[w * 2 + half][c2 * 2]     = ssq0;
    rq[w * 2 + half][c2 * 2 + 1] = ssq1;
    __syncthreads();
    if (tid < 128) {
        const int c = tid & 63;
        float v = 0.f;
        if (tid < 64) { for (int r = 0; r < 8; ++r) v += rs[r][c]; }
        else          { for (int r = 0; r < 8; ++r) v += rq[r][c]; }
        atomicAdd(&statsN[(g & 31) * 128 + tid], v);   // striped: ~64 adds/line
    }
}

// ---------------- Kernel 3: reduce-in-prologue + affine + leaky + transpose ----------------
__global__ __launch_bounds__(256) void out_kernel(
    const unsigned* __restrict__ hselp,      // (B,N,32) bf16-pairs
    const float* __restrict__ statsN,        // (32,128)
    const float* __restrict__ gamma,
    const float* __restrict__ beta,
    float* __restrict__ out)                 // (B, 64, N)
{
    __shared__ float tile[64 * 65];
    __shared__ float colsum[128];
    __shared__ float sc[64], bi[64];
    const int tid = threadIdx.x;

    if (tid < 128) {
        float v = 0.f;
        #pragma unroll
        for (int i = 0; i < 32; ++i) v += statsN[i * 128 + tid];
        colsum[tid] = v;
    }
    __syncthreads();
    if (tid < 64) {
        float mean = colsum[tid] * (1.0f / BNK_F);
        float var  = colsum[64 + tid] * (1.0f / BNK_F) - mean * mean;
        float s    = gamma[tid] * rsqrtf(var + 1e-5f);
        sc[tid] = s;
        bi[tid] = beta[tid] - mean * s;
    }
    __syncthreads();

    const int b  = blockIdx.x >> 8;
    const int n0 = (blockIdx.x & 255) << 6;
    const size_t bn0 = (size_t)b * NDIM + n0;
    const int c2 = tid & 31;

    for (int r = tid >> 5; r < 64; r += 8) {
        unsigned u = hselp[(bn0 + r) * 32 + c2];
        float v0 = fmaf(sc[2 * c2],     __uint_as_float(u << 16),          bi[2 * c2]);
        float v1 = fmaf(sc[2 * c2 + 1], __uint_as_float(u & 0xffff0000u), bi[2 * c2 + 1]);
        v0 = (v0 >= 0.f) ? v0 : 0.2f * v0;
        v1 = (v1 >= 0.f) ? v1 : 0.2f * v1;
        tile[r * 65 + 2 * c2]     = v0;
        tile[r * 65 + 2 * c2 + 1] = v1;
    }
    __syncthreads();
    const int lane = tid & 63;
    for (int o = tid >> 6; o < 64; o += 4)
        out[((size_t)(b * 64 + o) << 14) + n0 + lane] = tile[lane * 65 + o];
}

extern "C" void kernel_launch(void* const* d_in, const int* in_sizes, int n_in,
                              void* d_out, int out_size, void* d_ws, size_t ws_size,
                              hipStream_t stream) {
    const float* x     = (const float*)d_in[0];
    const int*   ei    = (const int*)d_in[1];
    const float* W     = (const float*)d_in[2];
    const float* gamma = (const float*)d_in[3];
    const float* beta  = (const float*)d_in[4];
    float* out = (float*)d_out;

    char* ws = (char*)d_ws;
    unsigned* y1p    = (unsigned*)(ws);                       // 8 MiB (bf16 pairs)
    unsigned* y2p    = (unsigned*)(ws + 8388608);             // 8 MiB
    unsigned* hselp  = (unsigned*)(ws + 16777216);            // 8 MiB
    float*    statsN = (float*)(ws + 25165824);               // 16 KiB (32x128)

    gemm_mfma_kernel <<<dim3(1024), dim3(256), 0, stream>>>(x, W, y1p, y2p, statsN);
    gather_kernel    <<<dim3(2048), dim3(256), 0, stream>>>(y1p, y2p, ei, gamma, hselp, statsN);
    out_kernel       <<<dim3(1024), dim3(256), 0, stream>>>(hselp, statsN, gamma, beta, out);
}